// Round 1
// baseline (304.675 us; speedup 1.0000x reference)
//
#include <hip/hip_runtime.h>
#include <math.h>

#define BS 2
#define NQ 21760
#define V_LEN 21760
#define EMBED 256
#define NH 8
#define NL 4
#define NP 4
#define HD 32

typedef __bf16 bf16;
typedef __bf16 bf16x8 __attribute__((ext_vector_type(8)));
typedef __bf16 bf16x4 __attribute__((ext_vector_type(4)));
typedef float f32x4 __attribute__((ext_vector_type(4)));

// async global->LDS, 16B per lane. LDS dest must be lane-linear (base + lane*16).
#define GLOAD_LDS16(gp, lp_) \
    __builtin_amdgcn_global_load_lds( \
        (const __attribute__((address_space(1))) unsigned int*)(gp), \
        (__attribute__((address_space(3))) unsigned int*)(lp_), 16, 0, 0)

// ---------------- weight transpose+cast: WT[n][k] = bf16(W[k][n]), K=256 fixed
__global__ __launch_bounds__(256) void cast_wt(const float* __restrict__ W,
                                               bf16* __restrict__ WT, int N)
{
    int id = blockIdx.x * 256 + threadIdx.x;   // total 256*N
    int n = id >> 8, k = id & 255;
    WT[id] = (bf16)W[k * N + n];
}

__global__ __launch_bounds__(384) void concat_bias(const float* __restrict__ b_off,
                                                   const float* __restrict__ b_attn,
                                                   float* __restrict__ bc)
{
    int id = threadIdx.x;  // 384
    bc[id] = (id < 256) ? b_off[id] : b_attn[id - 256];
}

// ---------------- bf16 MFMA GEMM: C[M,N] = A[M,K] @ WT^T + bias
// A: fp32 (stays fp32 in LDS, cvt after ds_read) or bf16. WT: [N][K] bf16.
// Tile 128x128, BK=32. Staging via global_load_lds dwordx4 (m97 structure).
// fp32-A LDS tile is chunk-XOR-swizzled (c ^= row&7) via pre-swizzled global src;
// bf16 [128][32] tiles are phase-optimal unswizzled.
template<bool A_F32, bool OUT_BF16>
__global__ __launch_bounds__(256) void gemm_mfma(
    const void* __restrict__ Av, const bf16* __restrict__ WT,
    const float* __restrict__ bias, void* __restrict__ Cv,
    int N, int K, int ntn)
{
    const int bnt = blockIdx.x % ntn;     // col-fastest: A panel reused by adjacent blocks
    const int bmt = blockIdx.x / ntn;
    const int bm = bmt * 128, bn = bnt * 128;

    __shared__ __align__(16) bf16 Bs[128 * 32];                          // 8 KB, linear
    __shared__ __align__(16) unsigned char AsRaw[A_F32 ? 128 * 32 * 4    // 16 KB f32
                                                       : 128 * 32 * 2]; // 8 KB bf16

    const int tid = threadIdx.x;
    const int lane = tid & 63, wv = tid >> 6;
    const int wr = wv >> 1, wc = wv & 1;
    const int quad = lane >> 4, l16 = lane & 15;

    f32x4 acc[4][4];
    #pragma unroll
    for (int i = 0; i < 4; i++)
        #pragma unroll
        for (int j = 0; j < 4; j++)
            acc[i][j] = (f32x4){0.f, 0.f, 0.f, 0.f};

    const int b_row = tid >> 2, b_chunk = tid & 3;   // bf16 staging: byte = p*4096 + tid*16
    const int a_row8 = tid >> 3, a_phys = tid & 7;   // f32 staging:  byte = p*4096 + tid*16

    for (int k0 = 0; k0 < K; k0 += 32) {
        if constexpr (A_F32) {
            const float* A = (const float*)Av;
            #pragma unroll
            for (int p = 0; p < 4; p++) {
                int row = a_row8 + p * 32;
                int csrc = a_phys ^ (row & 7);       // inverse-swizzled source chunk
                GLOAD_LDS16(&A[(size_t)(bm + row) * K + k0 + csrc * 4],
                            AsRaw + p * 4096 + tid * 16);
            }
        } else {
            const bf16* A = (const bf16*)Av;
            #pragma unroll
            for (int p = 0; p < 2; p++) {
                int row = b_row + p * 64;
                GLOAD_LDS16(&A[(size_t)(bm + row) * K + k0 + b_chunk * 8],
                            AsRaw + p * 4096 + tid * 16);
            }
        }
        #pragma unroll
        for (int p = 0; p < 2; p++) {
            int row = b_row + p * 64;
            GLOAD_LDS16(&WT[(size_t)(bn + row) * K + k0 + b_chunk * 8],
                        (unsigned char*)Bs + p * 4096 + tid * 16);
        }
        __syncthreads();   // drains vmcnt before any LDS read

        bf16x8 af[4], bfr[4];
        if constexpr (A_F32) {
            const float* Asf = (const float*)AsRaw;  // [128][32] f32, chunk-swizzled
            #pragma unroll
            for (int mi = 0; mi < 4; mi++) {
                int r = wr * 64 + mi * 16 + l16;
                int g = r & 7;
                f32x4 u0 = *(const f32x4*)&Asf[r * 32 + ((2 * quad) ^ g) * 4];
                f32x4 u1 = *(const f32x4*)&Asf[r * 32 + ((2 * quad + 1) ^ g) * 4];
                bf16x8 h;
                h[0] = (bf16)u0[0]; h[1] = (bf16)u0[1]; h[2] = (bf16)u0[2]; h[3] = (bf16)u0[3];
                h[4] = (bf16)u1[0]; h[5] = (bf16)u1[1]; h[6] = (bf16)u1[2]; h[7] = (bf16)u1[3];
                af[mi] = h;
            }
        } else {
            const bf16* Asb = (const bf16*)AsRaw;    // [128][32] bf16, linear
            #pragma unroll
            for (int mi = 0; mi < 4; mi++) {
                int r = wr * 64 + mi * 16 + l16;
                af[mi] = *(const bf16x8*)&Asb[r * 32 + quad * 8];
            }
        }
        #pragma unroll
        for (int ni = 0; ni < 4; ni++) {
            int r = wc * 64 + ni * 16 + l16;
            bfr[ni] = *(const bf16x8*)&Bs[r * 32 + quad * 8];
        }
        #pragma unroll
        for (int mi = 0; mi < 4; mi++)
            #pragma unroll
            for (int ni = 0; ni < 4; ni++)
                acc[mi][ni] = __builtin_amdgcn_mfma_f32_16x16x32_bf16(
                    af[mi], bfr[ni], acc[mi][ni], 0, 0, 0);
        __syncthreads();
    }

    // epilogue
    #pragma unroll
    for (int mi = 0; mi < 4; mi++) {
        #pragma unroll
        for (int ni = 0; ni < 4; ni++) {
            const int col = bn + wc * 64 + ni * 16 + l16;
            const int row0 = bm + wr * 64 + mi * 16 + quad * 4;
            const float bc = bias[col];
            #pragma unroll
            for (int r = 0; r < 4; r++) {
                float v = acc[mi][ni][r] + bc;
                if constexpr (OUT_BF16)
                    ((bf16*)Cv)[(size_t)(row0 + r) * N + col] = (bf16)v;
                else
                    ((float*)Cv)[(size_t)(row0 + r) * N + col] = v;
            }
        }
    }
}

// ---------------- Deformable sampling: 4 queries per 256-thread block (1 wave each).
// vproj: bf16 [BS,V,256]; offaw: fp32 [BS*NQ,384] (off 0..255, attn logits 256..383)
// sampled: bf16 [BS*NQ,256]
__global__ __launch_bounds__(256) void deform_sample(
    const bf16* __restrict__ vproj, const float* __restrict__ offaw,
    const float* __restrict__ refp, bf16* __restrict__ sampled)
{
    const int wv = threadIdx.x >> 6;          // wave = query slot
    const int t = threadIdx.x & 63;           // lane
    const int q = blockIdx.x * 4 + wv;
    const int b = blockIdx.y;
    const int bq = b * NQ + q;

    __shared__ __align__(16) float s_off[4][256];   // XOR-swizzled: idx j stored at j^(((j>>5)&7)<<2)
    __shared__ __align__(16) float s_aw[4][128];
    __shared__ __align__(16) float s_w[4][128][4];  // indexed [lp*8+h]
    __shared__ __align__(16) int   s_idx[4][128][4];

    const float* row = offaw + (size_t)bq * 384;
    #pragma unroll
    for (int i = 0; i < 4; i++) {
        int j = t + i * 64;
        s_off[wv][j ^ (((j >> 5) & 7) << 2)] = row[j];
    }
    #pragma unroll
    for (int i = 0; i < 2; i++) s_aw[wv][t + i * 64] = row[256 + t + i * 64];
    __syncthreads();

    // wave-parallel softmax: 8 lanes per head, 2 elems each, shfl_xor butterflies
    {
        const int h = t >> 3, e = t & 7;
        float v0 = s_aw[wv][h * 16 + e];
        float v1 = s_aw[wv][h * 16 + 8 + e];
        float m = fmaxf(v0, v1);
        m = fmaxf(m, __shfl_xor(m, 1));
        m = fmaxf(m, __shfl_xor(m, 2));
        m = fmaxf(m, __shfl_xor(m, 4));
        float e0 = __expf(v0 - m), e1 = __expf(v1 - m);
        float ssum = e0 + e1;
        ssum += __shfl_xor(ssum, 1);
        ssum += __shfl_xor(ssum, 2);
        ssum += __shfl_xor(ssum, 4);
        float rs = 1.0f / ssum;
        s_aw[wv][h * 16 + e] = e0 * rs;
        s_aw[wv][h * 16 + 8 + e] = e1 * rs;
    }
    __syncthreads();

    // precompute 128 samples. Mapping h=t&7, lp=(t>>3)+8*sI makes d == t+64*sI
    // -> consecutive, conflict-free s_idx/s_w b128 stores (was 16-way).
    #pragma unroll
    for (int sI = 0; sI < 2; sI++) {
        int h = t & 7;
        int lp = (t >> 3) + sI * 8;
        int l = lp >> 2, p = lp & 3;
        int Wl = 128 >> l, Hl = 128 >> l;
        int st = (l == 0) ? 0 : (l == 1) ? 16384 : (l == 2) ? 20480 : 21504;
        float rx = refp[((size_t)bq * 4 + l) * 2 + 0];
        float ry = refp[((size_t)bq * 4 + l) * 2 + 1];
        int j = h * 32 + lp * 2;                       // logical s_off index (j>>5 == h)
        float2 oxy = *(const float2*)&s_off[wv][j ^ (h << 2)];
        float ox = oxy.x, oy = oxy.y;
        float fW = (float)Wl, fH = (float)Hl;
        float x = (rx + ox / fW) * fW - 0.5f;
        float y = (ry + oy / fH) * fH - 0.5f;
        float xf = floorf(x), yf = floorf(y);
        int x0 = (int)xf, y0 = (int)yf;
        float wx1 = x - xf, wx0 = 1.f - wx1;
        float wy1 = y - yf, wy0 = 1.f - wy1;
        float aw = s_aw[wv][h * 16 + lp];
        bool vx0 = (x0 >= 0) && (x0 < Wl);
        bool vx1 = (x0 + 1 >= 0) && (x0 + 1 < Wl);
        bool vy0 = (y0 >= 0) && (y0 < Hl);
        bool vy1 = (y0 + 1 >= 0) && (y0 + 1 < Hl);
        int cx0 = min(max(x0, 0), Wl - 1), cx1 = min(max(x0 + 1, 0), Wl - 1);
        int cy0 = min(max(y0, 0), Hl - 1), cy1 = min(max(y0 + 1, 0), Hl - 1);
        int d = lp * 8 + h;  // == t + 64*sI
        s_idx[wv][d][0] = st + cy0 * Wl + cx0;  s_w[wv][d][0] = (vy0 && vx0) ? wy0 * wx0 * aw : 0.f;
        s_idx[wv][d][1] = st + cy0 * Wl + cx1;  s_w[wv][d][1] = (vy0 && vx1) ? wy0 * wx1 * aw : 0.f;
        s_idx[wv][d][2] = st + cy1 * Wl + cx0;  s_w[wv][d][2] = (vy1 && vx0) ? wy1 * wx0 * aw : 0.f;
        s_idx[wv][d][3] = st + cy1 * Wl + cx1;  s_w[wv][d][3] = (vy1 && vx1) ? wy1 * wx1 * aw : 0.f;
    }
    __syncthreads();

    // gather: lane t owns head h = t>>3, channels choff = t*4 .. t*4+3
    const int h = t >> 3;
    const int choff = t * 4;
    const bf16* vbc = vproj + (size_t)b * V_LEN * EMBED + choff;
    float a0 = 0.f, a1 = 0.f, a2 = 0.f, a3 = 0.f;
    #pragma unroll 4
    for (int lp = 0; lp < 16; lp++) {
        const int d = lp * 8 + h;
        const float4 w4 = *(const float4*)&s_w[wv][d][0];
        const int4  i4 = *(const int4*)&s_idx[wv][d][0];
        bf16x4 v0 = *(const bf16x4*)(vbc + (i4.x << 8));
        bf16x4 v1 = *(const bf16x4*)(vbc + (i4.y << 8));
        bf16x4 v2 = *(const bf16x4*)(vbc + (i4.z << 8));
        bf16x4 v3 = *(const bf16x4*)(vbc + (i4.w << 8));
        a0 += w4.x * (float)v0[0] + w4.y * (float)v1[0] + w4.z * (float)v2[0] + w4.w * (float)v3[0];
        a1 += w4.x * (float)v0[1] + w4.y * (float)v1[1] + w4.z * (float)v2[1] + w4.w * (float)v3[1];
        a2 += w4.x * (float)v0[2] + w4.y * (float)v1[2] + w4.z * (float)v2[2] + w4.w * (float)v3[2];
        a3 += w4.x * (float)v0[3] + w4.y * (float)v1[3] + w4.z * (float)v2[3] + w4.w * (float)v3[3];
    }

    bf16x4 o;
    o[0] = (bf16)a0; o[1] = (bf16)a1; o[2] = (bf16)a2; o[3] = (bf16)a3;
    *(bf16x4*)&sampled[(size_t)bq * 256 + choff] = o;
}

extern "C" void kernel_launch(void* const* d_in, const int* in_sizes, int n_in,
                              void* d_out, int out_size, void* d_ws, size_t ws_size,
                              hipStream_t stream)
{
    const float* query  = (const float*)d_in[0];
    const float* refp   = (const float*)d_in[1];
    const float* value  = (const float*)d_in[2];
    const float* W_off  = (const float*)d_in[3];
    const float* b_off  = (const float*)d_in[4];
    const float* W_attn = (const float*)d_in[5];
    const float* b_attn = (const float*)d_in[6];
    const float* W_v    = (const float*)d_in[7];
    const float* b_v    = (const float*)d_in[8];
    const float* W_out  = (const float*)d_in[9];
    const float* b_out  = (const float*)d_in[10];
    float* out = (float*)d_out;

    const int M = BS * NQ;  // 43520

    char* ws = (char*)d_ws;
    bf16*  WTv   = (bf16*)ws;                      ws += 256 * 256 * 2;
    bf16*  WToa  = (bf16*)ws;                      ws += 384 * 256 * 2;
    bf16*  WTu   = (bf16*)ws;                      ws += 256 * 256 * 2;
    float* bcat  = (float*)ws;                     ws += 384 * 4;
    bf16*  vproj = (bf16*)ws;                      ws += (size_t)M * 256 * 2;
    float* offaw = (float*)ws;                     ws += (size_t)M * 384 * 4;
    bf16*  samp  = (bf16*)ws;                      ws += (size_t)M * 256 * 2;

    cast_wt<<<256, 256, 0, stream>>>(W_v,   WTv, 256);
    cast_wt<<<256, 256, 0, stream>>>(W_off, WToa, 256);
    cast_wt<<<128, 256, 0, stream>>>(W_attn, WToa + 256 * 256, 128);
    cast_wt<<<256, 256, 0, stream>>>(W_out, WTu, 256);
    concat_bias<<<1, 384, 0, stream>>>(b_off, b_attn, bcat);

    // vproj = bf16(value @ W_v + b_v)
    gemm_mfma<true, true><<<(M / 128) * 2, 256, 0, stream>>>(value, WTv, b_v, vproj, 256, 256, 2);
    // offaw = query @ [W_off | W_attn] + [b_off | b_attn]   (fp32 out)
    gemm_mfma<true, false><<<(M / 128) * 3, 256, 0, stream>>>(query, WToa, bcat, offaw, 384, 256, 3);
    // softmax + deformable sampling -> bf16
    deform_sample<<<dim3(NQ / 4, BS), dim3(256), 0, stream>>>(vproj, offaw, refp, samp);
    // out = sampled @ W_out + b_out  (fp32 out)
    gemm_mfma<false, false><<<(M / 128) * 2, 256, 0, stream>>>(samp, WTu, b_out, out, 256, 256, 2);
}

// Round 2
// 293.754 us; speedup vs baseline: 1.0372x; 1.0372x over previous
//
#include <hip/hip_runtime.h>
#include <math.h>

#define BS 2
#define NQ 21760
#define V_LEN 21760
#define EMBED 256
#define NH 8
#define NL 4
#define NP 4
#define HD 32

typedef __bf16 bf16;
typedef __bf16 bf16x8 __attribute__((ext_vector_type(8)));
typedef __bf16 bf16x4 __attribute__((ext_vector_type(4)));
typedef float f32x4 __attribute__((ext_vector_type(4)));
typedef float f32x2 __attribute__((ext_vector_type(2)));
typedef unsigned int u32;

// async global->LDS, 16B per lane. LDS dest must be lane-linear (base + lane*16).
#define GLOAD_LDS16(gp, lp_) \
    __builtin_amdgcn_global_load_lds( \
        (const __attribute__((address_space(1))) unsigned int*)(gp), \
        (__attribute__((address_space(3))) unsigned int*)(lp_), 16, 0, 0)

// ---------------- fused prologue: all weight transposes+casts + bias concat (1 launch)
__global__ __launch_bounds__(256) void cast_all(
    const float* __restrict__ W_v, const float* __restrict__ W_off,
    const float* __restrict__ W_attn, const float* __restrict__ W_out,
    const float* __restrict__ b_off, const float* __restrict__ b_attn,
    bf16* __restrict__ WTv, bf16* __restrict__ WToa, bf16* __restrict__ WTu,
    float* __restrict__ bcat)
{
    const int bid = blockIdx.x;
    if (bid == 896) {
        int id = threadIdx.x;
        if (id < 384) bcat[id] = (id < 256) ? b_off[id] : b_attn[id - 256];
        return;
    }
    int id = bid * 256 + threadIdx.x;
    if (id < 65536) {
        int n = id >> 8, k = id & 255;
        WTv[id] = (bf16)W_v[k * 256 + n];
    } else if (id < 131072) {
        int j = id - 65536; int n = j >> 8, k = j & 255;
        WToa[j] = (bf16)W_off[k * 256 + n];
    } else if (id < 163840) {
        int j = id - 131072; int n = j >> 8, k = j & 255;
        WToa[65536 + j] = (bf16)W_attn[k * 128 + n];
    } else {
        int j = id - 163840; int n = j >> 8, k = j & 255;
        WTu[j] = (bf16)W_out[k * 256 + n];
    }
}

// ---------------- bf16 MFMA GEMM: C[M,N] = A[M,K] @ WT^T + bias
// Tile 128x128, BK=32. Double-buffered global_load_lds pipeline (T3 2-phase):
// STAGE(t+1) issued before compute(t); counted vmcnt(NB) + raw s_barrier —
// never drains vmcnt to 0 mid-loop, so the HBM latency of step t+1 hides
// under step t's ds_read+MFMA. fp32-A tile chunk-XOR-swizzled via source.
template<bool A_F32, bool OUT_BF16>
__global__ __launch_bounds__(256) void gemm_mfma(
    const void* __restrict__ Av, const bf16* __restrict__ WT,
    const float* __restrict__ bias, void* __restrict__ Cv,
    int N, int K, int ntn)
{
    const int bnt = blockIdx.x % ntn;     // col-fastest: A panel reused by adjacent blocks
    const int bmt = blockIdx.x / ntn;
    const int bm = bmt * 128, bn = bnt * 128;

    __shared__ __align__(16) bf16 Bs[2][128 * 32];                       // 2x8 KB
    __shared__ __align__(16) unsigned char AsRaw[2][A_F32 ? 128 * 32 * 4
                                                         : 128 * 32 * 2];

    const int tid = threadIdx.x;
    const int lane = tid & 63, wv = tid >> 6;
    const int wr = wv >> 1, wc = wv & 1;
    const int quad = lane >> 4, l16 = lane & 15;

    f32x4 acc[4][4];
    #pragma unroll
    for (int i = 0; i < 4; i++)
        #pragma unroll
        for (int j = 0; j < 4; j++)
            acc[i][j] = (f32x4){0.f, 0.f, 0.f, 0.f};

    const int b_row = tid >> 2, b_chunk = tid & 3;   // bf16 staging: byte = p*4096 + tid*16
    const int a_row8 = tid >> 3, a_phys = tid & 7;   // f32 staging:  byte = p*4096 + tid*16
    constexpr int NB = A_F32 ? 6 : 4;                // global_load_lds per wave per step

    auto stage = [&](int buf, int k0) {
        if constexpr (A_F32) {
            const float* A = (const float*)Av;
            #pragma unroll
            for (int p = 0; p < 4; p++) {
                int row = a_row8 + p * 32;
                int csrc = a_phys ^ (row & 7);       // inverse-swizzled source chunk
                GLOAD_LDS16(&A[(size_t)(bm + row) * K + k0 + csrc * 4],
                            &AsRaw[buf][p * 4096 + tid * 16]);
            }
        } else {
            const bf16* A = (const bf16*)Av;
            #pragma unroll
            for (int p = 0; p < 2; p++) {
                int row = b_row + p * 64;
                GLOAD_LDS16(&A[(size_t)(bm + row) * K + k0 + b_chunk * 8],
                            &AsRaw[buf][p * 4096 + tid * 16]);
            }
        }
        #pragma unroll
        for (int p = 0; p < 2; p++) {
            int row = b_row + p * 64;
            GLOAD_LDS16(&WT[(size_t)(bn + row) * K + k0 + b_chunk * 8],
                        (unsigned char*)&Bs[buf][0] + p * 4096 + tid * 16);
        }
    };

    const int nt = K >> 5;   // 8
    stage(0, 0);
    int cur = 0;
    for (int t = 0; t < nt; t++) {
        __builtin_amdgcn_s_barrier();               // prev step's LDS reads all done
        if (t + 1 < nt) {
            stage(cur ^ 1, (t + 1) << 5);           // prefetch next tile (stays in flight)
            asm volatile("s_waitcnt vmcnt(%0)" :: "n"(NB) : "memory");  // cur tile landed
        } else {
            asm volatile("s_waitcnt vmcnt(0)" ::: "memory");
        }
        __builtin_amdgcn_s_barrier();               // all waves' cur-tile loads landed

        bf16x8 af[4], bfr[4];
        if constexpr (A_F32) {
            const float* Asf = (const float*)&AsRaw[cur][0];  // [128][32] f32, chunk-swizzled
            #pragma unroll
            for (int mi = 0; mi < 4; mi++) {
                int r = wr * 64 + mi * 16 + l16;
                int g = r & 7;
                f32x4 u0 = *(const f32x4*)&Asf[r * 32 + ((2 * quad) ^ g) * 4];
                f32x4 u1 = *(const f32x4*)&Asf[r * 32 + ((2 * quad + 1) ^ g) * 4];
                bf16x8 hh;
                hh[0] = (bf16)u0[0]; hh[1] = (bf16)u0[1]; hh[2] = (bf16)u0[2]; hh[3] = (bf16)u0[3];
                hh[4] = (bf16)u1[0]; hh[5] = (bf16)u1[1]; hh[6] = (bf16)u1[2]; hh[7] = (bf16)u1[3];
                af[mi] = hh;
            }
        } else {
            const bf16* Asb = (const bf16*)&AsRaw[cur][0];    // [128][32] bf16, linear
            #pragma unroll
            for (int mi = 0; mi < 4; mi++) {
                int r = wr * 64 + mi * 16 + l16;
                af[mi] = *(const bf16x8*)&Asb[r * 32 + quad * 8];
            }
        }
        #pragma unroll
        for (int ni = 0; ni < 4; ni++) {
            int r = wc * 64 + ni * 16 + l16;
            bfr[ni] = *(const bf16x8*)&Bs[cur][r * 32 + quad * 8];
        }
        #pragma unroll
        for (int mi = 0; mi < 4; mi++)
            #pragma unroll
            for (int ni = 0; ni < 4; ni++)
                acc[mi][ni] = __builtin_amdgcn_mfma_f32_16x16x32_bf16(
                    af[mi], bfr[ni], acc[mi][ni], 0, 0, 0);
        cur ^= 1;
    }

    // epilogue
    #pragma unroll
    for (int mi = 0; mi < 4; mi++) {
        #pragma unroll
        for (int ni = 0; ni < 4; ni++) {
            const int col = bn + wc * 64 + ni * 16 + l16;
            const int row0 = bm + wr * 64 + mi * 16 + quad * 4;
            const float bc = bias[col];
            #pragma unroll
            for (int r = 0; r < 4; r++) {
                float v = acc[mi][ni][r] + bc;
                if constexpr (OUT_BF16)
                    ((bf16*)Cv)[(size_t)(row0 + r) * N + col] = (bf16)v;
                else
                    ((float*)Cv)[(size_t)(row0 + r) * N + col] = v;
            }
        }
    }
}

// ---------------- Deformable sampling: 4 queries per 256-thread block (1 wave each).
__global__ __launch_bounds__(256) void deform_sample(
    const bf16* __restrict__ vproj, const float* __restrict__ offaw,
    const float* __restrict__ refp, bf16* __restrict__ sampled)
{
    const int wv = threadIdx.x >> 6;          // wave = query slot
    const int t = threadIdx.x & 63;           // lane
    const int q = blockIdx.x * 4 + wv;
    const int b = blockIdx.y;
    const int bq = b * NQ + q;

    __shared__ __align__(16) float s_off[4][256];   // XOR-swizzled: idx j at j^(((j>>5)&7)<<2)
    __shared__ __align__(16) float s_aw[4][128];
    __shared__ __align__(16) float s_w[4][128][4];  // indexed [lp*8+h]
    __shared__ __align__(16) int   s_idx[4][128][4];

    const float* row = offaw + (size_t)bq * 384;
    #pragma unroll
    for (int i = 0; i < 4; i++) {
        int j = t + i * 64;
        s_off[wv][j ^ (((j >> 5) & 7) << 2)] = row[j];
    }
    #pragma unroll
    for (int i = 0; i < 2; i++) s_aw[wv][t + i * 64] = row[256 + t + i * 64];
    __syncthreads();

    // wave-parallel softmax: 8 lanes per head, 2 elems each, shfl_xor butterflies
    {
        const int h = t >> 3, e = t & 7;
        float v0 = s_aw[wv][h * 16 + e];
        float v1 = s_aw[wv][h * 16 + 8 + e];
        float m = fmaxf(v0, v1);
        m = fmaxf(m, __shfl_xor(m, 1));
        m = fmaxf(m, __shfl_xor(m, 2));
        m = fmaxf(m, __shfl_xor(m, 4));
        float e0 = __expf(v0 - m), e1 = __expf(v1 - m);
        float ssum = e0 + e1;
        ssum += __shfl_xor(ssum, 1);
        ssum += __shfl_xor(ssum, 2);
        ssum += __shfl_xor(ssum, 4);
        float rs = 1.0f / ssum;
        s_aw[wv][h * 16 + e] = e0 * rs;
        s_aw[wv][h * 16 + 8 + e] = e1 * rs;
    }
    __syncthreads();

    // precompute 128 samples; d == t + 64*sI -> conflict-free b128 stores
    #pragma unroll
    for (int sI = 0; sI < 2; sI++) {
        int h = t & 7;
        int lp = (t >> 3) + sI * 8;
        int l = lp >> 2, p = lp & 3;
        int Wl = 128 >> l, Hl = 128 >> l;
        int st = (l == 0) ? 0 : (l == 1) ? 16384 : (l == 2) ? 20480 : 21504;
        float rx = refp[((size_t)bq * 4 + l) * 2 + 0];
        float ry = refp[((size_t)bq * 4 + l) * 2 + 1];
        int j = h * 32 + lp * 2;                       // logical s_off index
        float2 oxy = *(const float2*)&s_off[wv][j ^ (h << 2)];
        float ox = oxy.x, oy = oxy.y;
        float fW = (float)Wl, fH = (float)Hl;
        float x = (rx + ox / fW) * fW - 0.5f;
        float y = (ry + oy / fH) * fH - 0.5f;
        float xf = floorf(x), yf = floorf(y);
        int x0 = (int)xf, y0 = (int)yf;
        float wx1 = x - xf, wx0 = 1.f - wx1;
        float wy1 = y - yf, wy0 = 1.f - wy1;
        float aw = s_aw[wv][h * 16 + lp];
        bool vx0 = (x0 >= 0) && (x0 < Wl);
        bool vx1 = (x0 + 1 >= 0) && (x0 + 1 < Wl);
        bool vy0 = (y0 >= 0) && (y0 < Hl);
        bool vy1 = (y0 + 1 >= 0) && (y0 + 1 < Hl);
        int cx0 = min(max(x0, 0), Wl - 1), cx1 = min(max(x0 + 1, 0), Wl - 1);
        int cy0 = min(max(y0, 0), Hl - 1), cy1 = min(max(y0 + 1, 0), Hl - 1);
        int d = lp * 8 + h;  // == t + 64*sI
        s_idx[wv][d][0] = st + cy0 * Wl + cx0;  s_w[wv][d][0] = (vy0 && vx0) ? wy0 * wx0 * aw : 0.f;
        s_idx[wv][d][1] = st + cy0 * Wl + cx1;  s_w[wv][d][1] = (vy0 && vx1) ? wy0 * wx1 * aw : 0.f;
        s_idx[wv][d][2] = st + cy1 * Wl + cx0;  s_w[wv][d][2] = (vy1 && vx0) ? wy1 * wx0 * aw : 0.f;
        s_idx[wv][d][3] = st + cy1 * Wl + cx1;  s_w[wv][d][3] = (vy1 && vx1) ? wy1 * wx1 * aw : 0.f;
    }
    __syncthreads();

    // gather: lane t owns head h = t>>3, channels choff = t*4 .. t*4+3
    // bf16->f32 via bit-shift (exact); packed f32x2 accumulate -> v_pk_fma_f32
    const int h = t >> 3;
    const int choff = t * 4;
    const bf16* vbc = vproj + (size_t)b * V_LEN * EMBED + choff;
    f32x2 acc01 = {0.f, 0.f}, acc23 = {0.f, 0.f};
    #pragma unroll 8
    for (int lp = 0; lp < 16; lp++) {
        const int d = lp * 8 + h;
        const float4 w4 = *(const float4*)&s_w[wv][d][0];
        const int4  i4 = *(const int4*)&s_idx[wv][d][0];
        uint2 r0 = *(const uint2*)(vbc + (i4.x << 8));
        uint2 r1 = *(const uint2*)(vbc + (i4.y << 8));
        uint2 r2 = *(const uint2*)(vbc + (i4.z << 8));
        uint2 r3 = *(const uint2*)(vbc + (i4.w << 8));
        f32x2 v;
        v[0] = __uint_as_float(r0.x << 16); v[1] = __uint_as_float(r0.x & 0xFFFF0000u);
        acc01 += v * w4.x;
        v[0] = __uint_as_float(r0.y << 16); v[1] = __uint_as_float(r0.y & 0xFFFF0000u);
        acc23 += v * w4.x;
        v[0] = __uint_as_float(r1.x << 16); v[1] = __uint_as_float(r1.x & 0xFFFF0000u);
        acc01 += v * w4.y;
        v[0] = __uint_as_float(r1.y << 16); v[1] = __uint_as_float(r1.y & 0xFFFF0000u);
        acc23 += v * w4.y;
        v[0] = __uint_as_float(r2.x << 16); v[1] = __uint_as_float(r2.x & 0xFFFF0000u);
        acc01 += v * w4.z;
        v[0] = __uint_as_float(r2.y << 16); v[1] = __uint_as_float(r2.y & 0xFFFF0000u);
        acc23 += v * w4.z;
        v[0] = __uint_as_float(r3.x << 16); v[1] = __uint_as_float(r3.x & 0xFFFF0000u);
        acc01 += v * w4.w;
        v[0] = __uint_as_float(r3.y << 16); v[1] = __uint_as_float(r3.y & 0xFFFF0000u);
        acc23 += v * w4.w;
    }

    bf16x4 o;
    o[0] = (bf16)acc01[0]; o[1] = (bf16)acc01[1];
    o[2] = (bf16)acc23[0]; o[3] = (bf16)acc23[1];
    *(bf16x4*)&sampled[(size_t)bq * 256 + choff] = o;
}

extern "C" void kernel_launch(void* const* d_in, const int* in_sizes, int n_in,
                              void* d_out, int out_size, void* d_ws, size_t ws_size,
                              hipStream_t stream)
{
    const float* query  = (const float*)d_in[0];
    const float* refp   = (const float*)d_in[1];
    const float* value  = (const float*)d_in[2];
    const float* W_off  = (const float*)d_in[3];
    const float* b_off  = (const float*)d_in[4];
    const float* W_attn = (const float*)d_in[5];
    const float* b_attn = (const float*)d_in[6];
    const float* W_v    = (const float*)d_in[7];
    const float* b_v    = (const float*)d_in[8];
    const float* W_out  = (const float*)d_in[9];
    const float* b_out  = (const float*)d_in[10];
    float* out = (float*)d_out;

    const int M = BS * NQ;  // 43520

    char* ws = (char*)d_ws;
    bf16*  WTv   = (bf16*)ws;                      ws += 256 * 256 * 2;
    bf16*  WToa  = (bf16*)ws;                      ws += 384 * 256 * 2;
    bf16*  WTu   = (bf16*)ws;                      ws += 256 * 256 * 2;
    float* bcat  = (float*)ws;                     ws += 384 * 4;
    bf16*  vproj = (bf16*)ws;                      ws += (size_t)M * 256 * 2;
    float* offaw = (float*)ws;                     ws += (size_t)M * 384 * 4;
    bf16*  samp  = (bf16*)ws;                      ws += (size_t)M * 256 * 2;

    cast_all<<<897, 256, 0, stream>>>(W_v, W_off, W_attn, W_out, b_off, b_attn,
                                      WTv, WToa, WTu, bcat);

    // vproj = bf16(value @ W_v + b_v)
    gemm_mfma<true, true><<<(M / 128) * 2, 256, 0, stream>>>(value, WTv, b_v, vproj, 256, 256, 2);
    // offaw = query @ [W_off | W_attn] + [b_off | b_attn]   (fp32 out)
    gemm_mfma<true, false><<<(M / 128) * 3, 256, 0, stream>>>(query, WToa, bcat, offaw, 384, 256, 3);
    // softmax + deformable sampling -> bf16
    deform_sample<<<dim3(NQ / 4, BS), dim3(256), 0, stream>>>(vproj, offaw, refp, samp);
    // out = sampled @ W_out + b_out  (fp32 out)
    gemm_mfma<false, false><<<(M / 128) * 2, 256, 0, stream>>>(samp, WTu, b_out, out, 256, 256, 2);
}

// Round 4
// 293.280 us; speedup vs baseline: 1.0389x; 1.0016x over previous
//
#include <hip/hip_runtime.h>
#include <math.h>

#define BS 2
#define NQ 21760
#define V_LEN 21760
#define EMBED 256
#define NH 8
#define NL 4
#define NP 4
#define HD 32

typedef __bf16 bf16;
typedef __bf16 bf16x8 __attribute__((ext_vector_type(8)));
typedef __bf16 bf16x4 __attribute__((ext_vector_type(4)));
typedef float f32x4 __attribute__((ext_vector_type(4)));
typedef float f32x2 __attribute__((ext_vector_type(2)));
typedef unsigned int u32;

// async global->LDS, 16B per lane. LDS dest must be lane-linear (base + lane*16).
#define GLOAD_LDS16(gp, lp_) \
    __builtin_amdgcn_global_load_lds( \
        (const __attribute__((address_space(1))) unsigned int*)(gp), \
        (__attribute__((address_space(3))) unsigned int*)(lp_), 16, 0, 0)

// ---------------- fused prologue: LDS-tiled transpose+cast of all weights + bias concat
// W matrices are [K=256][N]; output WT[n][k], bf16, row stride 256.
// Tiles: W_v 16 (4x4), W_off 16, W_attn 8 (4x2), W_out 16  => 56 + 1 bias block.
__global__ __launch_bounds__(256) void cast_all(
    const float* __restrict__ W_v, const float* __restrict__ W_off,
    const float* __restrict__ W_attn, const float* __restrict__ W_out,
    const float* __restrict__ b_off, const float* __restrict__ b_attn,
    bf16* __restrict__ WTv, bf16* __restrict__ WToa, bf16* __restrict__ WTu,
    float* __restrict__ bcat)
{
    const int bid = blockIdx.x;
    const int tid = threadIdx.x;
    if (bid == 56) {
        if (tid < 384) bcat[tid] = (tid < 256) ? b_off[tid] : b_attn[tid - 256];
        return;
    }
    const float* W; bf16* WT; int N, tile;
    if (bid < 16)      { W = W_v;    WT = WTv;           N = 256; tile = bid; }
    else if (bid < 32) { W = W_off;  WT = WToa;          N = 256; tile = bid - 16; }
    else if (bid < 40) { W = W_attn; WT = WToa + 65536;  N = 128; tile = bid - 32; }
    else               { W = W_out;  WT = WTu;           N = 256; tile = bid - 40; }
    const int ntn = N >> 6;
    const int k0 = (tile / ntn) * 64, n0 = (tile % ntn) * 64;

    __shared__ float lds[64][65];
    const int c = tid & 63, r4 = tid >> 6;
    #pragma unroll
    for (int p = 0; p < 16; p++) {
        int rr = r4 + p * 4;
        lds[rr][c] = W[(size_t)(k0 + rr) * N + n0 + c];   // coalesced 256B rows
    }
    __syncthreads();
    #pragma unroll
    for (int p = 0; p < 16; p++) {
        int i = r4 + p * 4;                                // n index
        WT[(size_t)(n0 + i) * 256 + k0 + c] = (bf16)lds[c][i];  // coalesced 128B rows
    }
}

// ---------------- bf16 MFMA GEMM: C[M,N] = A[M,K] @ WT^T + bias
// Tile 128x128, BK=32, 2-phase double-buffered global_load_lds pipeline.
// Block order ROW-fastest: consecutive blocks share only the (L2-resident)
// weight panel; each A panel is fetched from HBM once (L3 absorbs far reuse).
template<bool A_F32, bool OUT_BF16>
__global__ __launch_bounds__(256) void gemm_mfma(
    const void* __restrict__ Av, const bf16* __restrict__ WT,
    const float* __restrict__ bias, void* __restrict__ Cv,
    int N, int K, int ntn)
{
    const int nmt = gridDim.x / ntn;
    const int bmt = blockIdx.x % nmt;     // row-fastest
    const int bnt = blockIdx.x / nmt;
    const int bm = bmt * 128, bn = bnt * 128;

    __shared__ __align__(16) bf16 Bs[2][128 * 32];                       // 2x8 KB
    __shared__ __align__(16) unsigned char AsRaw[2][A_F32 ? 128 * 32 * 4
                                                         : 128 * 32 * 2];

    const int tid = threadIdx.x;
    const int lane = tid & 63, wv = tid >> 6;
    const int wr = wv >> 1, wc = wv & 1;
    const int quad = lane >> 4, l16 = lane & 15;

    f32x4 acc[4][4];
    #pragma unroll
    for (int i = 0; i < 4; i++)
        #pragma unroll
        for (int j = 0; j < 4; j++)
            acc[i][j] = (f32x4){0.f, 0.f, 0.f, 0.f};

    const int b_row = tid >> 2, b_chunk = tid & 3;   // bf16 staging: byte = p*4096 + tid*16
    const int a_row8 = tid >> 3, a_phys = tid & 7;   // f32 staging:  byte = p*4096 + tid*16
    constexpr int NB = A_F32 ? 6 : 4;                // global_load_lds per thread per step

    auto stage = [&](int buf, int k0) {
        if constexpr (A_F32) {
            const float* A = (const float*)Av;
            #pragma unroll
            for (int p = 0; p < 4; p++) {
                int row = a_row8 + p * 32;
                int csrc = a_phys ^ (row & 7);       // inverse-swizzled source chunk
                GLOAD_LDS16(&A[(size_t)(bm + row) * K + k0 + csrc * 4],
                            &AsRaw[buf][p * 4096 + tid * 16]);
            }
        } else {
            const bf16* A = (const bf16*)Av;
            #pragma unroll
            for (int p = 0; p < 2; p++) {
                int row = b_row + p * 64;
                GLOAD_LDS16(&A[(size_t)(bm + row) * K + k0 + b_chunk * 8],
                            &AsRaw[buf][p * 4096 + tid * 16]);
            }
        }
        #pragma unroll
        for (int p = 0; p < 2; p++) {
            int row = b_row + p * 64;
            GLOAD_LDS16(&WT[(size_t)(bn + row) * K + k0 + b_chunk * 8],
                        (unsigned char*)&Bs[buf][0] + p * 4096 + tid * 16);
        }
    };

    const int nt = K >> 5;   // 8
    stage(0, 0);
    int cur = 0;
    for (int t = 0; t < nt; t++) {
        __builtin_amdgcn_s_barrier();               // prev step's LDS reads all done
        if (t + 1 < nt) {
            stage(cur ^ 1, (t + 1) << 5);           // prefetch next tile (stays in flight)
            asm volatile("s_waitcnt vmcnt(%0)" :: "n"(NB) : "memory");  // cur tile landed
        } else {
            asm volatile("s_waitcnt vmcnt(0)" ::: "memory");
        }
        __builtin_amdgcn_s_barrier();               // all waves' cur-tile loads landed

        bf16x8 af[4], bfr[4];
        if constexpr (A_F32) {
            const float* Asf = (const float*)&AsRaw[cur][0];  // [128][32] f32, chunk-swizzled
            #pragma unroll
            for (int mi = 0; mi < 4; mi++) {
                int r = wr * 64 + mi * 16 + l16;
                int g = r & 7;
                f32x4 u0 = *(const f32x4*)&Asf[r * 32 + ((2 * quad) ^ g) * 4];
                f32x4 u1 = *(const f32x4*)&Asf[r * 32 + ((2 * quad + 1) ^ g) * 4];
                bf16x8 hh;
                hh[0] = (bf16)u0[0]; hh[1] = (bf16)u0[1]; hh[2] = (bf16)u0[2]; hh[3] = (bf16)u0[3];
                hh[4] = (bf16)u1[0]; hh[5] = (bf16)u1[1]; hh[6] = (bf16)u1[2]; hh[7] = (bf16)u1[3];
                af[mi] = hh;
            }
        } else {
            const bf16* Asb = (const bf16*)&AsRaw[cur][0];    // [128][32] bf16, linear
            #pragma unroll
            for (int mi = 0; mi < 4; mi++) {
                int r = wr * 64 + mi * 16 + l16;
                af[mi] = *(const bf16x8*)&Asb[r * 32 + quad * 8];
            }
        }
        #pragma unroll
        for (int ni = 0; ni < 4; ni++) {
            int r = wc * 64 + ni * 16 + l16;
            bfr[ni] = *(const bf16x8*)&Bs[cur][r * 32 + quad * 8];
        }
        #pragma unroll
        for (int mi = 0; mi < 4; mi++)
            #pragma unroll
            for (int ni = 0; ni < 4; ni++)
                acc[mi][ni] = __builtin_amdgcn_mfma_f32_16x16x32_bf16(
                    af[mi], bfr[ni], acc[mi][ni], 0, 0, 0);
        cur ^= 1;
    }

    // epilogue
    #pragma unroll
    for (int mi = 0; mi < 4; mi++) {
        #pragma unroll
        for (int ni = 0; ni < 4; ni++) {
            const int col = bn + wc * 64 + ni * 16 + l16;
            const int row0 = bm + wr * 64 + mi * 16 + quad * 4;
            const float bc = bias[col];
            #pragma unroll
            for (int r = 0; r < 4; r++) {
                float v = acc[mi][ni][r] + bc;
                if constexpr (OUT_BF16)
                    ((bf16*)Cv)[(size_t)(row0 + r) * N + col] = (bf16)v;
                else
                    ((float*)Cv)[(size_t)(row0 + r) * N + col] = v;
            }
        }
    }
}

// ---------------- Deformable sampling: 4 queries per 256-thread block (1 wave each).
// Register-resident offsets + in-register softmax (stride-{8,16,32} butterflies).
// Gather: 16B/lane loads, 4 lanes/head, wave halves split the 16 lp values;
// halves combined with shfl_xor(.,32). One __syncthreads total.
__global__ __launch_bounds__(256) void deform_sample(
    const bf16* __restrict__ vproj, const float* __restrict__ offaw,
    const float* __restrict__ refp, bf16* __restrict__ sampled)
{
    const int wv = threadIdx.x >> 6;          // wave = query slot
    const int t = threadIdx.x & 63;           // lane
    const int q = blockIdx.x * 4 + wv;
    const int b = blockIdx.y;
    const int bq = b * NQ + q;

    __shared__ __align__(16) float s_w[4][128][4];  // indexed [lp*8+h]
    __shared__ __align__(16) int   s_idx[4][128][4];

    const float* row = offaw + (size_t)bq * 384;

    // ---- in-register softmax: lane owns (h = t&7, e = t>>3); logits for lp=e, e+8
    const int hp = t & 7, e = t >> 3;
    float l0 = row[256 + hp * 16 + e];
    float l1 = row[256 + hp * 16 + e + 8];
    float m = fmaxf(l0, l1);
    m = fmaxf(m, __shfl_xor(m, 8));
    m = fmaxf(m, __shfl_xor(m, 16));
    m = fmaxf(m, __shfl_xor(m, 32));
    float e0 = __expf(l0 - m), e1 = __expf(l1 - m);
    float ssum = e0 + e1;
    ssum += __shfl_xor(ssum, 8);
    ssum += __shfl_xor(ssum, 16);
    ssum += __shfl_xor(ssum, 32);
    float rs = 1.0f / ssum;
    float awv[2] = {e0 * rs, e1 * rs};

    // ---- precompute 128 samples; d == t + 64*sI -> conflict-free b128 stores
    #pragma unroll
    for (int sI = 0; sI < 2; sI++) {
        int lp = e + sI * 8;
        int l = lp >> 2;
        int Wl = 128 >> l, Hl = 128 >> l;
        int st = (l == 0) ? 0 : (l == 1) ? 16384 : (l == 2) ? 20480 : 21504;
        float2 rp = *(const float2*)&refp[((size_t)bq * 4 + l) * 2];
        float2 oxy = *(const float2*)&row[hp * 32 + lp * 2];
        float fW = (float)Wl, fH = (float)Hl;
        float x = (rp.x + oxy.x / fW) * fW - 0.5f;
        float y = (rp.y + oxy.y / fH) * fH - 0.5f;
        float xf = floorf(x), yf = floorf(y);
        int x0 = (int)xf, y0 = (int)yf;
        float wx1 = x - xf, wx0 = 1.f - wx1;
        float wy1 = y - yf, wy0 = 1.f - wy1;
        float aw = awv[sI];
        bool vx0 = (x0 >= 0) && (x0 < Wl);
        bool vx1 = (x0 + 1 >= 0) && (x0 + 1 < Wl);
        bool vy0 = (y0 >= 0) && (y0 < Hl);
        bool vy1 = (y0 + 1 >= 0) && (y0 + 1 < Hl);
        int cx0 = min(max(x0, 0), Wl - 1), cx1 = min(max(x0 + 1, 0), Wl - 1);
        int cy0 = min(max(y0, 0), Hl - 1), cy1 = min(max(y0 + 1, 0), Hl - 1);
        int d = lp * 8 + hp;  // == t + 64*sI
        s_idx[wv][d][0] = st + cy0 * Wl + cx0;  s_w[wv][d][0] = (vy0 && vx0) ? wy0 * wx0 * aw : 0.f;
        s_idx[wv][d][1] = st + cy0 * Wl + cx1;  s_w[wv][d][1] = (vy0 && vx1) ? wy0 * wx1 * aw : 0.f;
        s_idx[wv][d][2] = st + cy1 * Wl + cx0;  s_w[wv][d][2] = (vy1 && vx0) ? wy1 * wx0 * aw : 0.f;
        s_idx[wv][d][3] = st + cy1 * Wl + cx1;  s_w[wv][d][3] = (vy1 && vx1) ? wy1 * wx1 * aw : 0.f;
    }
    __syncthreads();

    // ---- gather: half = t>>5 owns lp = lpp + 8*half; 4 lanes per head, 16B each.
    const int half = t >> 5;
    const int hg = (t & 31) >> 2;             // head
    const int cg = t & 3;                     // 8-channel group within head
    const int choff = hg * 32 + cg * 8;
    const bf16* vbc = vproj + (size_t)b * V_LEN * EMBED + choff;

    f32x2 a01 = {0.f, 0.f}, a23 = {0.f, 0.f}, a45 = {0.f, 0.f}, a67 = {0.f, 0.f};
    #pragma unroll
    for (int lpp = 0; lpp < 8; lpp++) {
        const int d = (lpp + 8 * half) * 8 + hg;
        const float4 w4 = *(const float4*)&s_w[wv][d][0];
        const int4  i4 = *(const int4*)&s_idx[wv][d][0];
        uint4 r0 = *(const uint4*)(vbc + ((size_t)i4.x << 8));
        uint4 r1 = *(const uint4*)(vbc + ((size_t)i4.y << 8));
        uint4 r2 = *(const uint4*)(vbc + ((size_t)i4.z << 8));
        uint4 r3 = *(const uint4*)(vbc + ((size_t)i4.w << 8));
        f32x2 v;
        #define ACC8(rr, ww) \
            v[0] = __uint_as_float((rr).x << 16); v[1] = __uint_as_float((rr).x & 0xFFFF0000u); a01 += v * (ww); \
            v[0] = __uint_as_float((rr).y << 16); v[1] = __uint_as_float((rr).y & 0xFFFF0000u); a23 += v * (ww); \
            v[0] = __uint_as_float((rr).z << 16); v[1] = __uint_as_float((rr).z & 0xFFFF0000u); a45 += v * (ww); \
            v[0] = __uint_as_float((rr).w << 16); v[1] = __uint_as_float((rr).w & 0xFFFF0000u); a67 += v * (ww);
        ACC8(r0, w4.x)
        ACC8(r1, w4.y)
        ACC8(r2, w4.z)
        ACC8(r3, w4.w)
        #undef ACC8
    }

    // combine wave halves (lp 0-7 + lp 8-15)
    float s[8] = {a01[0], a01[1], a23[0], a23[1], a45[0], a45[1], a67[0], a67[1]};
    #pragma unroll
    for (int i = 0; i < 8; i++) s[i] += __shfl_xor(s[i], 32);

    if (t < 32) {
        bf16x8 o;
        #pragma unroll
        for (int i = 0; i < 8; i++) o[i] = (bf16)s[i];
        *(bf16x8*)&sampled[(size_t)bq * 256 + choff] = o;
    }
}

extern "C" void kernel_launch(void* const* d_in, const int* in_sizes, int n_in,
                              void* d_out, int out_size, void* d_ws, size_t ws_size,
                              hipStream_t stream)
{
    const float* query  = (const float*)d_in[0];
    const float* refp   = (const float*)d_in[1];
    const float* value  = (const float*)d_in[2];
    const float* W_off  = (const float*)d_in[3];
    const float* b_off  = (const float*)d_in[4];
    const float* W_attn = (const float*)d_in[5];
    const float* b_attn = (const float*)d_in[6];
    const float* W_v    = (const float*)d_in[7];
    const float* b_v    = (const float*)d_in[8];
    const float* W_out  = (const float*)d_in[9];
    const float* b_out  = (const float*)d_in[10];
    float* out = (float*)d_out;

    const int M = BS * NQ;  // 43520

    char* ws = (char*)d_ws;
    bf16*  WTv   = (bf16*)ws;                      ws += 256 * 256 * 2;
    bf16*  WToa  = (bf16*)ws;                      ws += 384 * 256 * 2;
    bf16*  WTu   = (bf16*)ws;                      ws += 256 * 256 * 2;
    float* bcat  = (float*)ws;                     ws += 384 * 4;
    bf16*  vproj = (bf16*)ws;                      ws += (size_t)M * 256 * 2;
    float* offaw = (float*)ws;                     ws += (size_t)M * 384 * 4;
    bf16*  samp  = (bf16*)ws;                      ws += (size_t)M * 256 * 2;

    cast_all<<<57, 256, 0, stream>>>(W_v, W_off, W_attn, W_out, b_off, b_attn,
                                     WTv, WToa, WTu, bcat);

    // vproj = bf16(value @ W_v + b_v)
    gemm_mfma<true, true><<<(M / 128) * 2, 256, 0, stream>>>(value, WTv, b_v, vproj, 256, 256, 2);
    // offaw = query @ [W_off | W_attn] + [b_off | b_attn]   (fp32 out)
    gemm_mfma<true, false><<<(M / 128) * 3, 256, 0, stream>>>(query, WToa, bcat, offaw, 384, 256, 3);
    // softmax + deformable sampling -> bf16
    deform_sample<<<dim3(NQ / 4, BS), dim3(256), 0, stream>>>(vproj, offaw, refp, samp);
    // out = sampled @ W_out + b_out  (fp32 out)
    gemm_mfma<false, false><<<(M / 128) * 2, 256, 0, stream>>>(samp, WTu, b_out, out, 256, 256, 2);
}

// Round 5
// 283.472 us; speedup vs baseline: 1.0748x; 1.0346x over previous
//
#include <hip/hip_runtime.h>
#include <math.h>

#define BS 2
#define NQ 21760
#define V_LEN 21760
#define EMBED 256
#define NH 8
#define NL 4
#define NP 4
#define HD 32

typedef __bf16 bf16;
typedef __bf16 bf16x8 __attribute__((ext_vector_type(8)));
typedef __bf16 bf16x4 __attribute__((ext_vector_type(4)));
typedef float f32x4 __attribute__((ext_vector_type(4)));
typedef float f32x2 __attribute__((ext_vector_type(2)));
typedef unsigned int u32;

// async global->LDS, 16B per lane. LDS dest must be lane-linear (base + lane*16).
#define GLOAD_LDS16(gp, lp_) \
    __builtin_amdgcn_global_load_lds( \
        (const __attribute__((address_space(1))) unsigned int*)(gp), \
        (__attribute__((address_space(3))) unsigned int*)(lp_), 16, 0, 0)

// ---------------- fused prologue: LDS-tiled transpose+cast of all weights + bias concat
__global__ __launch_bounds__(256) void cast_all(
    const float* __restrict__ W_v, const float* __restrict__ W_off,
    const float* __restrict__ W_attn, const float* __restrict__ W_out,
    const float* __restrict__ b_off, const float* __restrict__ b_attn,
    bf16* __restrict__ WTv, bf16* __restrict__ WToa, bf16* __restrict__ WTu,
    float* __restrict__ bcat)
{
    const int bid = blockIdx.x;
    const int tid = threadIdx.x;
    if (bid == 56) {
        if (tid < 384) bcat[tid] = (tid < 256) ? b_off[tid] : b_attn[tid - 256];
        return;
    }
    const float* W; bf16* WT; int N, tile;
    if (bid < 16)      { W = W_v;    WT = WTv;           N = 256; tile = bid; }
    else if (bid < 32) { W = W_off;  WT = WToa;          N = 256; tile = bid - 16; }
    else if (bid < 40) { W = W_attn; WT = WToa + 65536;  N = 128; tile = bid - 32; }
    else               { W = W_out;  WT = WTu;           N = 256; tile = bid - 40; }
    const int ntn = N >> 6;
    const int k0 = (tile / ntn) * 64, n0 = (tile % ntn) * 64;

    __shared__ float lds[64][65];
    const int c = tid & 63, r4 = tid >> 6;
    #pragma unroll
    for (int p = 0; p < 16; p++) {
        int rr = r4 + p * 4;
        lds[rr][c] = W[(size_t)(k0 + rr) * N + n0 + c];   // coalesced 256B rows
    }
    __syncthreads();
    #pragma unroll
    for (int p = 0; p < 16; p++) {
        int i = r4 + p * 4;                                // n index
        WT[(size_t)(n0 + i) * 256 + k0 + c] = (bf16)lds[c][i];  // coalesced 128B rows
    }
}

// ---------------- bf16 MFMA GEMM: C[M,N] = A[M,K] @ WT^T + bias
// OUT_MODE: 0 = fp32 linear, 1 = bf16 linear, 2 = bf16 per-head vproj layout
//           vproj[b][h][v][32] with global row rv -> (b = rv>=V_LEN, v = rv - b*V_LEN)
template<bool A_F32, int OUT_MODE>
__global__ __launch_bounds__(256) void gemm_mfma(
    const void* __restrict__ Av, const bf16* __restrict__ WT,
    const float* __restrict__ bias, void* __restrict__ Cv,
    int N, int K, int ntn)
{
    const int nmt = gridDim.x / ntn;
    const int bmt = blockIdx.x % nmt;     // row-fastest
    const int bnt = blockIdx.x / nmt;
    const int bm = bmt * 128, bn = bnt * 128;

    __shared__ __align__(16) bf16 Bs[2][128 * 32];                       // 2x8 KB
    __shared__ __align__(16) unsigned char AsRaw[2][A_F32 ? 128 * 32 * 4
                                                         : 128 * 32 * 2];

    const int tid = threadIdx.x;
    const int lane = tid & 63, wv = tid >> 6;
    const int wr = wv >> 1, wc = wv & 1;
    const int quad = lane >> 4, l16 = lane & 15;

    f32x4 acc[4][4];
    #pragma unroll
    for (int i = 0; i < 4; i++)
        #pragma unroll
        for (int j = 0; j < 4; j++)
            acc[i][j] = (f32x4){0.f, 0.f, 0.f, 0.f};

    const int b_row = tid >> 2, b_chunk = tid & 3;   // bf16 staging: byte = p*4096 + tid*16
    const int a_row8 = tid >> 3, a_phys = tid & 7;   // f32 staging:  byte = p*4096 + tid*16
    constexpr int NB = A_F32 ? 6 : 4;                // global_load_lds per thread per step

    auto stage = [&](int buf, int k0) {
        if constexpr (A_F32) {
            const float* A = (const float*)Av;
            #pragma unroll
            for (int p = 0; p < 4; p++) {
                int row = a_row8 + p * 32;
                int csrc = a_phys ^ (row & 7);       // inverse-swizzled source chunk
                GLOAD_LDS16(&A[(size_t)(bm + row) * K + k0 + csrc * 4],
                            &AsRaw[buf][p * 4096 + tid * 16]);
            }
        } else {
            const bf16* A = (const bf16*)Av;
            #pragma unroll
            for (int p = 0; p < 2; p++) {
                int row = b_row + p * 64;
                GLOAD_LDS16(&A[(size_t)(bm + row) * K + k0 + b_chunk * 8],
                            &AsRaw[buf][p * 4096 + tid * 16]);
            }
        }
        #pragma unroll
        for (int p = 0; p < 2; p++) {
            int row = b_row + p * 64;
            GLOAD_LDS16(&WT[(size_t)(bn + row) * K + k0 + b_chunk * 8],
                        (unsigned char*)&Bs[buf][0] + p * 4096 + tid * 16);
        }
    };

    const int nt = K >> 5;   // 8
    stage(0, 0);
    int cur = 0;
    for (int t = 0; t < nt; t++) {
        __builtin_amdgcn_s_barrier();               // prev step's LDS reads all done
        if (t + 1 < nt) {
            stage(cur ^ 1, (t + 1) << 5);           // prefetch next tile (stays in flight)
            asm volatile("s_waitcnt vmcnt(%0)" :: "n"(NB) : "memory");  // cur tile landed
        } else {
            asm volatile("s_waitcnt vmcnt(0)" ::: "memory");
        }
        __builtin_amdgcn_s_barrier();               // all waves' cur-tile loads landed

        bf16x8 af[4], bfr[4];
        if constexpr (A_F32) {
            const float* Asf = (const float*)&AsRaw[cur][0];  // [128][32] f32, chunk-swizzled
            #pragma unroll
            for (int mi = 0; mi < 4; mi++) {
                int r = wr * 64 + mi * 16 + l16;
                int g = r & 7;
                f32x4 u0 = *(const f32x4*)&Asf[r * 32 + ((2 * quad) ^ g) * 4];
                f32x4 u1 = *(const f32x4*)&Asf[r * 32 + ((2 * quad + 1) ^ g) * 4];
                bf16x8 hh;
                hh[0] = (bf16)u0[0]; hh[1] = (bf16)u0[1]; hh[2] = (bf16)u0[2]; hh[3] = (bf16)u0[3];
                hh[4] = (bf16)u1[0]; hh[5] = (bf16)u1[1]; hh[6] = (bf16)u1[2]; hh[7] = (bf16)u1[3];
                af[mi] = hh;
            }
        } else {
            const bf16* Asb = (const bf16*)&AsRaw[cur][0];    // [128][32] bf16, linear
            #pragma unroll
            for (int mi = 0; mi < 4; mi++) {
                int r = wr * 64 + mi * 16 + l16;
                af[mi] = *(const bf16x8*)&Asb[r * 32 + quad * 8];
            }
        }
        #pragma unroll
        for (int ni = 0; ni < 4; ni++) {
            int r = wc * 64 + ni * 16 + l16;
            bfr[ni] = *(const bf16x8*)&Bs[cur][r * 32 + quad * 8];
        }
        #pragma unroll
        for (int mi = 0; mi < 4; mi++)
            #pragma unroll
            for (int ni = 0; ni < 4; ni++)
                acc[mi][ni] = __builtin_amdgcn_mfma_f32_16x16x32_bf16(
                    af[mi], bfr[ni], acc[mi][ni], 0, 0, 0);
        cur ^= 1;
    }

    // epilogue
    #pragma unroll
    for (int mi = 0; mi < 4; mi++) {
        #pragma unroll
        for (int ni = 0; ni < 4; ni++) {
            const int col = bn + wc * 64 + ni * 16 + l16;
            const int row0 = bm + wr * 64 + mi * 16 + quad * 4;
            const float bc = bias[col];
            #pragma unroll
            for (int r = 0; r < 4; r++) {
                float v = acc[mi][ni][r] + bc;
                if constexpr (OUT_MODE == 0) {
                    ((float*)Cv)[(size_t)(row0 + r) * N + col] = v;
                } else if constexpr (OUT_MODE == 1) {
                    ((bf16*)Cv)[(size_t)(row0 + r) * N + col] = (bf16)v;
                } else {
                    int rv = row0 + r;
                    int bb = (rv >= V_LEN) ? 1 : 0;
                    int vv = rv - bb * V_LEN;
                    ((bf16*)Cv)[((size_t)(bb * NH + (col >> 5)) * V_LEN + vv) * 32
                                + (col & 31)] = (bf16)v;
                }
            }
        }
    }
}

// 8-channel bf16->f32 unpack + weighted accumulate into 4 packed f32x2
__device__ inline void acc8(const uint4& rr, float ww,
                            f32x2& a01, f32x2& a23, f32x2& a45, f32x2& a67)
{
    f32x2 v;
    v[0] = __uint_as_float(rr.x << 16); v[1] = __uint_as_float(rr.x & 0xFFFF0000u); a01 += v * ww;
    v[0] = __uint_as_float(rr.y << 16); v[1] = __uint_as_float(rr.y & 0xFFFF0000u); a23 += v * ww;
    v[0] = __uint_as_float(rr.z << 16); v[1] = __uint_as_float(rr.z & 0xFFFF0000u); a45 += v * ww;
    v[0] = __uint_as_float(rr.w << 16); v[1] = __uint_as_float(rr.w & 0xFFFF0000u); a67 += v * ww;
}

// ---------------- Deformable sampling: 4 queries per 256-thread block (1 wave each).
// vproj per-head layout [b][h][v][32ch]. Each bilinear sample reads TWO contiguous
// 128B row-pairs (x-slot pair at px,px+1; rows py,py+1) — every fetched cacheline
// fully used. Border cases folded into the 4 slot weights (exact same products).
__global__ __launch_bounds__(256) void deform_sample(
    const bf16* __restrict__ vproj, const float* __restrict__ offaw,
    const float* __restrict__ refp, bf16* __restrict__ sampled)
{
    const int wv = threadIdx.x >> 6;          // wave = query slot
    const int t = threadIdx.x & 63;           // lane
    const int q = blockIdx.x * 4 + wv;
    const int b = blockIdx.y;
    const int bq = b * NQ + q;

    __shared__ __align__(16) float s_w[4][128][4];  // slot weights, indexed [lp*8+h]
    __shared__ __align__(16) int   s_idx[4][128];   // pair base index (st + py*W + px)

    const float* row = offaw + (size_t)bq * 384;

    // ---- in-register softmax: lane owns (h = t&7, e = t>>3); logits for lp=e, e+8
    const int hp = t & 7, e = t >> 3;
    float l0 = row[256 + hp * 16 + e];
    float l1 = row[256 + hp * 16 + e + 8];
    float m = fmaxf(l0, l1);
    m = fmaxf(m, __shfl_xor(m, 8));
    m = fmaxf(m, __shfl_xor(m, 16));
    m = fmaxf(m, __shfl_xor(m, 32));
    float e0 = __expf(l0 - m), e1 = __expf(l1 - m);
    float ssum = e0 + e1;
    ssum += __shfl_xor(ssum, 8);
    ssum += __shfl_xor(ssum, 16);
    ssum += __shfl_xor(ssum, 32);
    float rs = 1.0f / ssum;
    float awv[2] = {e0 * rs, e1 * rs};

    // ---- precompute 128 samples as (pair base, 4 slot weights); d == t + 64*sI
    #pragma unroll
    for (int sI = 0; sI < 2; sI++) {
        int lp = e + sI * 8;
        int l = lp >> 2;
        int Wl = 128 >> l, Hl = 128 >> l;
        int st = (l == 0) ? 0 : (l == 1) ? 16384 : (l == 2) ? 20480 : 21504;
        float2 rp = *(const float2*)&refp[((size_t)bq * 4 + l) * 2];
        float2 oxy = *(const float2*)&row[hp * 32 + lp * 2];
        float fW = (float)Wl, fH = (float)Hl;
        float x = (rp.x + oxy.x / fW) * fW - 0.5f;
        float y = (rp.y + oxy.y / fH) * fH - 0.5f;
        float xf = floorf(x), yf = floorf(y);
        int x0 = (int)xf, y0 = (int)yf;
        float wx1 = x - xf, wx0 = 1.f - wx1;
        float wy1 = y - yf, wy0 = 1.f - wy1;
        float aw = awv[sI];
        // validity-masked corner weights
        float wx0p = ((x0 >= 0) && (x0 < Wl)) ? wx0 : 0.f;
        float wx1p = ((x0 + 1 >= 0) && (x0 + 1 < Wl)) ? wx1 : 0.f;
        float wy0p = ((y0 >= 0) && (y0 < Hl)) ? wy0 : 0.f;
        float wy1p = ((y0 + 1 >= 0) && (y0 + 1 < Hl)) ? wy1 : 0.f;
        // clamped pair bases + slot weights (absorb clamping exactly)
        int px = min(max(x0, 0), Wl - 2), py = min(max(y0, 0), Hl - 2);
        int cx0 = min(max(x0, 0), Wl - 1), cx1 = min(max(x0 + 1, 0), Wl - 1);
        int cy0 = min(max(y0, 0), Hl - 1), cy1 = min(max(y0 + 1, 0), Hl - 1);
        float sx0 = ((cx0 == px) ? wx0p : 0.f) + ((cx1 == px) ? wx1p : 0.f);
        float sx1 = ((cx0 == px + 1) ? wx0p : 0.f) + ((cx1 == px + 1) ? wx1p : 0.f);
        float sy0 = ((cy0 == py) ? wy0p : 0.f) + ((cy1 == py) ? wy1p : 0.f);
        float sy1 = ((cy0 == py + 1) ? wy0p : 0.f) + ((cy1 == py + 1) ? wy1p : 0.f);
        int d = lp * 8 + hp;  // == t + 64*sI
        s_idx[wv][d] = st + py * Wl + px;
        s_w[wv][d][0] = sy0 * sx0 * aw;
        s_w[wv][d][1] = sy0 * sx1 * aw;
        s_w[wv][d][2] = sy1 * sx0 * aw;
        s_w[wv][d][3] = sy1 * sx1 * aw;
    }
    __syncthreads();

    // ---- gather: 8 lanes per head (h = t>>3, j = t&7).
    // Lane j reads 16B of the 128B x-pair: x-slot = j>>2, channels (j&3)*8..+7.
    const int h = t >> 3, j = t & 7;
    const bf16* vb = vproj + ((size_t)(b * NH + h) * V_LEN) * 32 + j * 8;

    f32x2 a01 = {0.f, 0.f}, a23 = {0.f, 0.f}, a45 = {0.f, 0.f}, a67 = {0.f, 0.f};
    #pragma unroll
    for (int lp = 0; lp < 16; lp++) {
        const int Wl = 128 >> (lp >> 2);          // compile-time per unrolled iter
        const int d = lp * 8 + h;
        const int base = s_idx[wv][d];
        const float4 w4 = *(const float4*)&s_w[wv][d][0];
        const bf16* p0 = vb + (size_t)base * 32;
        uint4 r0 = *(const uint4*)p0;             // row py
        uint4 r1 = *(const uint4*)(p0 + Wl * 32); // row py+1
        const bool xs = (j & 4) != 0;
        float wA = xs ? w4.y : w4.x;
        float wB = xs ? w4.w : w4.z;
        acc8(r0, wA, a01, a23, a45, a67);
        acc8(r1, wB, a01, a23, a45, a67);
    }

    // combine x-slots (lanes j and j^4 hold same channels)
    float s[8] = {a01[0], a01[1], a23[0], a23[1], a45[0], a45[1], a67[0], a67[1]};
    #pragma unroll
    for (int i = 0; i < 8; i++) s[i] += __shfl_xor(s[i], 4);

    if ((t & 4) == 0) {
        bf16x8 o;
        #pragma unroll
        for (int i = 0; i < 8; i++) o[i] = (bf16)s[i];
        *(bf16x8*)&sampled[(size_t)bq * 256 + h * 32 + (t & 3) * 8] = o;
    }
}

extern "C" void kernel_launch(void* const* d_in, const int* in_sizes, int n_in,
                              void* d_out, int out_size, void* d_ws, size_t ws_size,
                              hipStream_t stream)
{
    const float* query  = (const float*)d_in[0];
    const float* refp   = (const float*)d_in[1];
    const float* value  = (const float*)d_in[2];
    const float* W_off  = (const float*)d_in[3];
    const float* b_off  = (const float*)d_in[4];
    const float* W_attn = (const float*)d_in[5];
    const float* b_attn = (const float*)d_in[6];
    const float* W_v    = (const float*)d_in[7];
    const float* b_v    = (const float*)d_in[8];
    const float* W_out  = (const float*)d_in[9];
    const float* b_out  = (const float*)d_in[10];
    float* out = (float*)d_out;

    const int M = BS * NQ;  // 43520

    char* ws = (char*)d_ws;
    bf16*  WTv   = (bf16*)ws;                      ws += 256 * 256 * 2;
    bf16*  WToa  = (bf16*)ws;                      ws += 384 * 256 * 2;
    bf16*  WTu   = (bf16*)ws;                      ws += 256 * 256 * 2;
    float* bcat  = (float*)ws;                     ws += 384 * 4;
    bf16*  vproj = (bf16*)ws;                      ws += (size_t)M * 256 * 2;   // per-head layout
    float* offaw = (float*)ws;                     ws += (size_t)M * 384 * 4;
    bf16*  samp  = (bf16*)ws;                      ws += (size_t)M * 256 * 2;

    cast_all<<<57, 256, 0, stream>>>(W_v, W_off, W_attn, W_out, b_off, b_attn,
                                     WTv, WToa, WTu, bcat);

    // vproj = bf16(value @ W_v + b_v), written in per-head layout [b][h][v][32]
    gemm_mfma<true, 2><<<(M / 128) * 2, 256, 0, stream>>>(value, WTv, b_v, vproj, 256, 256, 2);
    // offaw = query @ [W_off | W_attn] + [b_off | b_attn]   (fp32 out)
    gemm_mfma<true, 0><<<(M / 128) * 3, 256, 0, stream>>>(query, WToa, bcat, offaw, 384, 256, 3);
    // softmax + deformable sampling -> bf16
    deform_sample<<<dim3(NQ / 4, BS), dim3(256), 0, stream>>>(vproj, offaw, refp, samp);
    // out = sampled @ W_out + b_out  (fp32 out)
    gemm_mfma<false, 0><<<(M / 128) * 2, 256, 0, stream>>>(samp, WTu, b_out, out, 256, 256, 2);
}